// Round 6
// baseline (273.504 us; speedup 1.0000x reference)
//
#include <hip/hip_runtime.h>
#include <hip/hip_fp16.h>
#include <math.h>

#define BATCH 16384
#define MAXF 32
#define NFEAT 768
#define FT_OUT 1024

#define CHUNK 32
#define NC_LDS 22                       // chunks 0..21 -> cols 0..703 via LDS
#define LDS_COLS (NC_LDS * CHUNK)       // 704
#define L2_COLS (FT_OUT - LDS_COLS)     // 320
#define NDC 5                           // L2 double-chunks of 64 cols
#define G_LDS 24                        // sample-group stripes for LDS role
#define G_L2 48                         // sample-group stripes for L2 role
#define NBLOCKS 768                     // 48*16; per 16: 11 LDS + 5 L2 (3 blocks/CU)
#define NCONTRIB (NC_LDS + NDC)         // 27 contributions per sample

// compile-time component select for unrolled loops (f is a constant after unroll)
#define GET4(a, f) (((f) & 3) == 0 ? (a)[(f) >> 2].x : \
                    ((f) & 3) == 1 ? (a)[(f) >> 2].y : \
                    ((f) & 3) == 2 ? (a)[(f) >> 2].z : (a)[(f) >> 2].w)

typedef unsigned int uint_t;

// Convert ONLY the L2-region columns (704..1023) to f16, row-major [768][320].
__global__ __launch_bounds__(256) void convert_l2_kernel(const float* __restrict__ ft_w,
                                                         __half* __restrict__ tab_l2) {
    const int i = (blockIdx.x * 256 + threadIdx.x) * 4;   // 0 .. 768*320-1
    const int r = i / L2_COLS;
    const int cw = i - r * L2_COLS;
    const float4 f = *(const float4*)(ft_w + (size_t)r * FT_OUT + LDS_COLS + cw);
    __half2 h0 = __floats2half2_rn(f.x, f.y);
    __half2 h1 = __floats2half2_rn(f.z, f.w);
    __half2* dst = (__half2*)(tab_l2 + (size_t)r * L2_COLS + cw);
    dst[0] = h0;
    dst[1] = h1;
}

__global__ __launch_bounds__(256, 3) void nnboard_main(
    const float* __restrict__ values,
    const int*   __restrict__ stm_idx,
    const int*   __restrict__ nstm_idx,
    const float* __restrict__ ft_w,
    const __half* __restrict__ tab_l2,
    const float* __restrict__ ft_b,
    const float* __restrict__ out_w,
    const float* __restrict__ out_b,
    float*       __restrict__ logits,
    int*         __restrict__ counts,
    float*       __restrict__ out)
{
    __shared__ __half s_tab[NFEAT * CHUNK];   // 48 KiB (unused by L2 role)

    const int tid = threadIdx.x;
    const int m = blockIdx.x & 15;
    const int q = blockIdx.x >> 4;            // 0..47
    const float ob = out_b[0];
    const __half2 zero2 = __float2half2_rn(0.f);

    if (m < 11) {
        // ================= LDS role: chunk c, stripe g =================
        const int lds_id = q * 11 + m;        // 0..527
        const int c = lds_id % NC_LDS;
        const int g = lds_id / NC_LDS;        // 0..23

        // stage chunk c from fp32 ft_w (R5-proven): 8 lanes/row, 128 B coalesced
        {
            const int lane8 = tid & 7;
            const int rbase = tid >> 3;
            #pragma unroll
            for (int k = 0; k < NFEAT / 32; ++k) {
                const int r = k * 32 + rbase;
                const float4 f = *(const float4*)(ft_w + (size_t)r * FT_OUT + c * CHUNK + lane8 * 4);
                __half2 h0 = __floats2half2_rn(f.x, f.y);
                __half2 h1 = __floats2half2_rn(f.z, f.w);
                uint2 u;
                u.x = *reinterpret_cast<uint_t*>(&h0);
                u.y = *reinterpret_cast<uint_t*>(&h1);
                *(uint2*)(s_tab + r * CHUNK + lane8 * 4) = u;
            }
        }
        __syncthreads();

        const int grp = tid >> 2;             // 0..63 sample slot
        const int j   = tid & 3;              // lane in group (8 cols)
        const int col0 = c * CHUNK + j * 8;
        const __half* my_tab = s_tab + j * 8; // + row*CHUNK

        const float4 bia0 = *(const float4*)(ft_b + col0);
        const float4 bia1 = *(const float4*)(ft_b + col0 + 4);
        const float4 ws0  = *(const float4*)(out_w + col0);
        const float4 ws1  = *(const float4*)(out_w + col0 + 4);
        const float4 wn0  = *(const float4*)(out_w + FT_OUT + col0);
        const float4 wn1  = *(const float4*)(out_w + FT_OUT + col0 + 4);

        for (int it = g; it < BATCH / 64; it += G_LDS) {
            const int b = it * 64 + grp;
            const int4*   sp = (const int4*)(stm_idx + b * MAXF);
            const int4*   np = (const int4*)(nstm_idx + b * MAXF);
            const float4* vp = (const float4*)(values + b * MAXF);
            int4 si[8], ni[8];
            float4 vv[8];
            #pragma unroll
            for (int k = 0; k < 8; ++k) { si[k] = sp[k]; ni[k] = np[k]; vv[k] = vp[k]; }

            __half2 accs[4] = {zero2, zero2, zero2, zero2};
            __half2 accn[4] = {zero2, zero2, zero2, zero2};

            #pragma unroll
            for (int f = 0; f < MAXF; ++f) {
                const int is = GET4(si, f);
                const int in = GET4(ni, f);
                const __half2 v2 = __float2half2_rn(GET4(vv, f));
                const uint4 qs = *(const uint4*)(my_tab + is * CHUNK);
                const uint4 qn = *(const uint4*)(my_tab + in * CHUNK);
                accs[0] = __hfma2(*(const __half2*)&qs.x, v2, accs[0]);
                accs[1] = __hfma2(*(const __half2*)&qs.y, v2, accs[1]);
                accs[2] = __hfma2(*(const __half2*)&qs.z, v2, accs[2]);
                accs[3] = __hfma2(*(const __half2*)&qs.w, v2, accs[3]);
                accn[0] = __hfma2(*(const __half2*)&qn.x, v2, accn[0]);
                accn[1] = __hfma2(*(const __half2*)&qn.y, v2, accn[1]);
                accn[2] = __hfma2(*(const __half2*)&qn.z, v2, accn[2]);
                accn[3] = __hfma2(*(const __half2*)&qn.w, v2, accn[3]);
            }

            float p = 0.f;
            {
                const float2 f0 = __half22float2(accs[0]);
                const float2 f1 = __half22float2(accs[1]);
                const float2 f2 = __half22float2(accs[2]);
                const float2 f3 = __half22float2(accs[3]);
                const float2 g0 = __half22float2(accn[0]);
                const float2 g1 = __half22float2(accn[1]);
                const float2 g2 = __half22float2(accn[2]);
                const float2 g3 = __half22float2(accn[3]);
                auto clip = [](float x) { return fminf(fmaxf(x, 0.f), 1.f); };
                p = fmaf(clip(f0.x + bia0.x), ws0.x, p);
                p = fmaf(clip(f0.y + bia0.y), ws0.y, p);
                p = fmaf(clip(f1.x + bia0.z), ws0.z, p);
                p = fmaf(clip(f1.y + bia0.w), ws0.w, p);
                p = fmaf(clip(f2.x + bia1.x), ws1.x, p);
                p = fmaf(clip(f2.y + bia1.y), ws1.y, p);
                p = fmaf(clip(f3.x + bia1.z), ws1.z, p);
                p = fmaf(clip(f3.y + bia1.w), ws1.w, p);
                p = fmaf(clip(g0.x + bia0.x), wn0.x, p);
                p = fmaf(clip(g0.y + bia0.y), wn0.y, p);
                p = fmaf(clip(g1.x + bia0.z), wn0.z, p);
                p = fmaf(clip(g1.y + bia0.w), wn0.w, p);
                p = fmaf(clip(g2.x + bia1.x), wn1.x, p);
                p = fmaf(clip(g2.y + bia1.y), wn1.y, p);
                p = fmaf(clip(g3.x + bia1.z), wn1.z, p);
                p = fmaf(clip(g3.y + bia1.w), wn1.w, p);
            }

            p += __shfl_down(p, 1, 64);
            p += __shfl_down(p, 2, 64);
            if (j == 0) atomicAdd(logits + b, p);
        }

        __threadfence();
        __syncthreads();
        if (tid < 64) {
            for (int it = g; it < BATCH / 64; it += G_LDS) {
                const int b = it * 64 + tid;
                const int cnt = atomicAdd(counts + b, 1);
                if (cnt == NCONTRIB - 1) {
                    __threadfence();
                    const float l = atomicAdd(logits + b, 0.f);
                    out[b] = 1.f / (1.f + expf(-(l + ob)));
                }
            }
        }
    } else {
        // ================= L2 role: double-chunk dc, stripe g2 =================
        const int l2_id = q * 5 + (m - 11);   // 0..239
        const int dc = l2_id % NDC;
        const int g2 = l2_id / NDC;           // 0..47

        const int grp = tid >> 3;             // 0..31 sample slot
        const int j   = tid & 7;              // lane in group (8 cols)
        const int col0 = LDS_COLS + dc * 64 + j * 8;
        const __half* my_tab = tab_l2 + dc * 64 + j * 8;  // + row*L2_COLS

        const float4 bia0 = *(const float4*)(ft_b + col0);
        const float4 bia1 = *(const float4*)(ft_b + col0 + 4);
        const float4 ws0  = *(const float4*)(out_w + col0);
        const float4 ws1  = *(const float4*)(out_w + col0 + 4);
        const float4 wn0  = *(const float4*)(out_w + FT_OUT + col0);
        const float4 wn1  = *(const float4*)(out_w + FT_OUT + col0 + 4);

        for (int it = g2; it < BATCH / 32; it += G_L2) {
            const int b = it * 32 + grp;
            const int4*   sp = (const int4*)(stm_idx + b * MAXF);
            const int4*   np = (const int4*)(nstm_idx + b * MAXF);
            const float4* vp = (const float4*)(values + b * MAXF);
            int4 si[8], ni[8];
            float4 vv[8];
            #pragma unroll
            for (int k = 0; k < 8; ++k) { si[k] = sp[k]; ni[k] = np[k]; vv[k] = vp[k]; }

            __half2 accs[4] = {zero2, zero2, zero2, zero2};
            __half2 accn[4] = {zero2, zero2, zero2, zero2};

            #pragma unroll
            for (int f = 0; f < MAXF; ++f) {
                const int is = GET4(si, f);
                const int in = GET4(ni, f);
                const __half2 v2 = __float2half2_rn(GET4(vv, f));
                const uint4 qs = *(const uint4*)(my_tab + is * L2_COLS);
                const uint4 qn = *(const uint4*)(my_tab + in * L2_COLS);
                accs[0] = __hfma2(*(const __half2*)&qs.x, v2, accs[0]);
                accs[1] = __hfma2(*(const __half2*)&qs.y, v2, accs[1]);
                accs[2] = __hfma2(*(const __half2*)&qs.z, v2, accs[2]);
                accs[3] = __hfma2(*(const __half2*)&qs.w, v2, accs[3]);
                accn[0] = __hfma2(*(const __half2*)&qn.x, v2, accn[0]);
                accn[1] = __hfma2(*(const __half2*)&qn.y, v2, accn[1]);
                accn[2] = __hfma2(*(const __half2*)&qn.z, v2, accn[2]);
                accn[3] = __hfma2(*(const __half2*)&qn.w, v2, accn[3]);
            }

            float p = 0.f;
            {
                const float2 f0 = __half22float2(accs[0]);
                const float2 f1 = __half22float2(accs[1]);
                const float2 f2 = __half22float2(accs[2]);
                const float2 f3 = __half22float2(accs[3]);
                const float2 g0 = __half22float2(accn[0]);
                const float2 g1 = __half22float2(accn[1]);
                const float2 g2 = __half22float2(accn[2]);
                const float2 g3 = __half22float2(accn[3]);
                auto clip = [](float x) { return fminf(fmaxf(x, 0.f), 1.f); };
                p = fmaf(clip(f0.x + bia0.x), ws0.x, p);
                p = fmaf(clip(f0.y + bia0.y), ws0.y, p);
                p = fmaf(clip(f1.x + bia0.z), ws0.z, p);
                p = fmaf(clip(f1.y + bia0.w), ws0.w, p);
                p = fmaf(clip(f2.x + bia1.x), ws1.x, p);
                p = fmaf(clip(f2.y + bia1.y), ws1.y, p);
                p = fmaf(clip(f3.x + bia1.z), ws1.z, p);
                p = fmaf(clip(f3.y + bia1.w), ws1.w, p);
                p = fmaf(clip(g0.x + bia0.x), wn0.x, p);
                p = fmaf(clip(g0.y + bia0.y), wn0.y, p);
                p = fmaf(clip(g1.x + bia0.z), wn0.z, p);
                p = fmaf(clip(g1.y + bia0.w), wn0.w, p);
                p = fmaf(clip(g2.x + bia1.x), wn1.x, p);
                p = fmaf(clip(g2.y + bia1.y), wn1.y, p);
                p = fmaf(clip(g3.x + bia1.z), wn1.z, p);
                p = fmaf(clip(g3.y + bia1.w), wn1.w, p);
            }

            p += __shfl_down(p, 1, 64);
            p += __shfl_down(p, 2, 64);
            p += __shfl_down(p, 4, 64);
            if (j == 0) atomicAdd(logits + b, p);
        }

        __threadfence();
        __syncthreads();
        if (tid < 32) {
            for (int it = g2; it < BATCH / 32; it += G_L2) {
                const int b = it * 32 + tid;
                const int cnt = atomicAdd(counts + b, 1);
                if (cnt == NCONTRIB - 1) {
                    __threadfence();
                    const float l = atomicAdd(logits + b, 0.f);
                    out[b] = 1.f / (1.f + expf(-(l + ob)));
                }
            }
        }
    }
}

extern "C" void kernel_launch(void* const* d_in, const int* in_sizes, int n_in,
                              void* d_out, int out_size, void* d_ws, size_t ws_size,
                              hipStream_t stream) {
    const float* values   = (const float*)d_in[0];
    const int*   stm_idx  = (const int*)d_in[1];
    const int*   nstm_idx = (const int*)d_in[2];
    const float* ft_w     = (const float*)d_in[3];
    const float* ft_b     = (const float*)d_in[4];
    const float* out_w    = (const float*)d_in[5];
    const float* out_b    = (const float*)d_in[6];
    float*       out      = (float*)d_out;

    float*  logits = (float*)d_ws;                                   // 64 KB
    int*    counts = (int*)((char*)d_ws + BATCH * sizeof(float));    // 64 KB
    __half* tab_l2 = (__half*)((char*)d_ws + 2 * BATCH * sizeof(float)); // 480 KB

    hipMemsetAsync(d_ws, 0, 2 * BATCH * sizeof(float), stream);
    convert_l2_kernel<<<(NFEAT * L2_COLS) / (256 * 4), 256, 0, stream>>>(ft_w, tab_l2);
    nnboard_main<<<NBLOCKS, 256, 0, stream>>>(
        values, stm_idx, nstm_idx, ft_w, tab_l2, ft_b, out_w, out_b,
        logits, counts, out);
}

// Round 7
// 183.426 us; speedup vs baseline: 1.4911x; 1.4911x over previous
//
#include <hip/hip_runtime.h>
#include <hip/hip_fp16.h>
#include <math.h>

#define BATCH 16384
#define MAXF 32
#define NFEAT 768
#define FT_OUT 1024
#define CHUNK 64                      // columns per chunk: row = 128 B = all 32 banks
#define NCHUNK (FT_OUT / CHUNK)       // 16 chunks
#define STRIPES 16                    // sample stripes -> 256 blocks = 1/CU
#define LDS_BYTES (NFEAT * CHUNK * 2) // 96 KiB dynamic LDS

// compile-time component select for unrolled loops (f is a constant after unroll)
#define GET4(a, f) (((f) & 3) == 0 ? (a)[(f) >> 2].x : \
                    ((f) & 3) == 1 ? (a)[(f) >> 2].y : \
                    ((f) & 3) == 2 ? (a)[(f) >> 2].z : (a)[(f) >> 2].w)

typedef unsigned int uint_t;

// One kernel: stage fp32 chunk -> f16 LDS (128-B rows, conflict-free), stream
// samples, fused sigmoid epilogue via per-sample arrival counters.
__global__ __launch_bounds__(512, 2) void nnboard_main(
    const float* __restrict__ values,
    const int*   __restrict__ stm_idx,
    const int*   __restrict__ nstm_idx,
    const float* __restrict__ ft_w,
    const float* __restrict__ ft_b,
    const float* __restrict__ out_w,
    const float* __restrict__ out_b,
    float*       __restrict__ logits,
    int*         __restrict__ counts,
    float*       __restrict__ out)
{
    extern __shared__ __half s_tab[];     // [NFEAT][CHUNK] = 96 KiB, row = 128 B

    const int tid = threadIdx.x;
    const int c = blockIdx.x & 15;        // chunk: cols [64c, 64c+64)
    const int g = blockIdx.x >> 4;        // stripe 0..15
    const float ob = out_b[0];
    const __half2 zero2 = __float2half2_rn(0.f);

    // ---- stage chunk c from fp32: 8 lanes per row, each converts 8 cols (32 B src)
    {
        const int lane8 = tid & 7;        // 16-B dest piece within the 128-B row
        const int rbase = tid >> 3;       // 64 rows per sweep
        #pragma unroll
        for (int k = 0; k < NFEAT / 64; ++k) {
            const int r = k * 64 + rbase;
            const float* src = ft_w + (size_t)r * FT_OUT + c * CHUNK + lane8 * 8;
            const float4 f0 = *(const float4*)(src);
            const float4 f1 = *(const float4*)(src + 4);
            __half2 h0 = __floats2half2_rn(f0.x, f0.y);
            __half2 h1 = __floats2half2_rn(f0.z, f0.w);
            __half2 h2 = __floats2half2_rn(f1.x, f1.y);
            __half2 h3 = __floats2half2_rn(f1.z, f1.w);
            uint4 u;
            u.x = *reinterpret_cast<uint_t*>(&h0);
            u.y = *reinterpret_cast<uint_t*>(&h1);
            u.z = *reinterpret_cast<uint_t*>(&h2);
            u.w = *reinterpret_cast<uint_t*>(&h3);
            *(uint4*)(s_tab + r * CHUNK + lane8 * 8) = u;
        }
    }
    __syncthreads();

    const int grp = tid >> 3;             // 0..63 : sample slot per iteration
    const int j   = tid & 3 ? (tid & 7) : (tid & 7);  // lane in sample (8 cols)
    const int jj  = tid & 7;
    const int col0 = c * CHUNK + jj * 8;
    const __half* my_tab = s_tab + jj * 8;   // + row*CHUNK per gathered row

    const float4 bia0 = *(const float4*)(ft_b + col0);
    const float4 bia1 = *(const float4*)(ft_b + col0 + 4);
    const float4 ws0  = *(const float4*)(out_w + col0);
    const float4 ws1  = *(const float4*)(out_w + col0 + 4);
    const float4 wn0  = *(const float4*)(out_w + FT_OUT + col0);
    const float4 wn1  = *(const float4*)(out_w + FT_OUT + col0 + 4);

    for (int it = g; it < BATCH / 64; it += STRIPES) {
        const int b = it * 64 + grp;

        const int4*   sp = (const int4*)(stm_idx + b * MAXF);
        const int4*   np = (const int4*)(nstm_idx + b * MAXF);
        const float4* vp = (const float4*)(values + b * MAXF);
        int4 si[8], ni[8];
        float4 vv[8];
        #pragma unroll
        for (int k = 0; k < 8; ++k) { si[k] = sp[k]; ni[k] = np[k]; vv[k] = vp[k]; }

        __half2 accs[4] = {zero2, zero2, zero2, zero2};
        __half2 accn[4] = {zero2, zero2, zero2, zero2};

        #pragma unroll
        for (int f = 0; f < MAXF; ++f) {
            const int is = GET4(si, f);
            const int in = GET4(ni, f);
            const __half2 v2 = __float2half2_rn(GET4(vv, f));
            const uint4 qs = *(const uint4*)(my_tab + is * CHUNK);
            const uint4 qn = *(const uint4*)(my_tab + in * CHUNK);
            accs[0] = __hfma2(*(const __half2*)&qs.x, v2, accs[0]);
            accs[1] = __hfma2(*(const __half2*)&qs.y, v2, accs[1]);
            accs[2] = __hfma2(*(const __half2*)&qs.z, v2, accs[2]);
            accs[3] = __hfma2(*(const __half2*)&qs.w, v2, accs[3]);
            accn[0] = __hfma2(*(const __half2*)&qn.x, v2, accn[0]);
            accn[1] = __hfma2(*(const __half2*)&qn.y, v2, accn[1]);
            accn[2] = __hfma2(*(const __half2*)&qn.z, v2, accn[2]);
            accn[3] = __hfma2(*(const __half2*)&qn.w, v2, accn[3]);
        }

        float p = 0.f;
        {
            const float2 f0 = __half22float2(accs[0]);
            const float2 f1 = __half22float2(accs[1]);
            const float2 f2 = __half22float2(accs[2]);
            const float2 f3 = __half22float2(accs[3]);
            const float2 g0 = __half22float2(accn[0]);
            const float2 g1 = __half22float2(accn[1]);
            const float2 g2 = __half22float2(accn[2]);
            const float2 g3 = __half22float2(accn[3]);
            auto clip = [](float x) { return fminf(fmaxf(x, 0.f), 1.f); };
            p = fmaf(clip(f0.x + bia0.x), ws0.x, p);
            p = fmaf(clip(f0.y + bia0.y), ws0.y, p);
            p = fmaf(clip(f1.x + bia0.z), ws0.z, p);
            p = fmaf(clip(f1.y + bia0.w), ws0.w, p);
            p = fmaf(clip(f2.x + bia1.x), ws1.x, p);
            p = fmaf(clip(f2.y + bia1.y), ws1.y, p);
            p = fmaf(clip(f3.x + bia1.z), ws1.z, p);
            p = fmaf(clip(f3.y + bia1.w), ws1.w, p);
            p = fmaf(clip(g0.x + bia0.x), wn0.x, p);
            p = fmaf(clip(g0.y + bia0.y), wn0.y, p);
            p = fmaf(clip(g1.x + bia0.z), wn0.z, p);
            p = fmaf(clip(g1.y + bia0.w), wn0.w, p);
            p = fmaf(clip(g2.x + bia1.x), wn1.x, p);
            p = fmaf(clip(g2.y + bia1.y), wn1.y, p);
            p = fmaf(clip(g3.x + bia1.z), wn1.z, p);
            p = fmaf(clip(g3.y + bia1.w), wn1.w, p);
        }

        // reduce 8 lanes of the sample group (aligned: tid = grp*8 + jj)
        p += __shfl_down(p, 1, 64);
        p += __shfl_down(p, 2, 64);
        p += __shfl_down(p, 4, 64);
        if (jj == 0) atomicAdd(logits + b, p);
    }

    // ---- fused epilogue: last contributor per sample applies sigmoid
    __threadfence();
    __syncthreads();

    if (tid < 64) {
        for (int it = g; it < BATCH / 64; it += STRIPES) {
            const int b = it * 64 + tid;
            const int cnt = atomicAdd(counts + b, 1);
            if (cnt == NCHUNK - 1) {
                __threadfence();
                const float l = atomicAdd(logits + b, 0.f);
                out[b] = 1.f / (1.f + expf(-(l + ob)));
            }
        }
    }
}

extern "C" void kernel_launch(void* const* d_in, const int* in_sizes, int n_in,
                              void* d_out, int out_size, void* d_ws, size_t ws_size,
                              hipStream_t stream) {
    const float* values   = (const float*)d_in[0];
    const int*   stm_idx  = (const int*)d_in[1];
    const int*   nstm_idx = (const int*)d_in[2];
    const float* ft_w     = (const float*)d_in[3];
    const float* ft_b     = (const float*)d_in[4];
    const float* out_w    = (const float*)d_in[5];
    const float* out_b    = (const float*)d_in[6];
    float*       out      = (float*)d_out;

    float* logits = (float*)d_ws;                                 // 64 KB
    int*   counts = (int*)((char*)d_ws + BATCH * sizeof(float));  // 64 KB

    // allow 96 KiB dynamic LDS (static limit is 64 KiB)
    static bool attr_set = false;
    (void)attr_set;
    hipFuncSetAttribute((const void*)nnboard_main,
                        hipFuncAttributeMaxDynamicSharedMemorySize, LDS_BYTES);

    hipMemsetAsync(d_ws, 0, 2 * BATCH * sizeof(float), stream);
    nnboard_main<<<NCHUNK * STRIPES, 512, LDS_BYTES, stream>>>(
        values, stm_idx, nstm_idx, ft_w, ft_b, out_w, out_b, logits, counts, out);
}